// Round 10
// baseline (302.451 us; speedup 1.0000x reference)
//
#include <hip/hip_runtime.h>
#include <hip/hip_bf16.h>

// Problem constants
constexpr int kB  = 1024;
constexpr int kV  = 6890;
constexpr int kJ  = 24;
constexpr int kNB = 10;
constexpr int kP  = 207;   // 23*9
constexpr int kH  = 17;

constexpr int kN   = kV * 3;      // 20670
constexpr int kKP  = 224;         // K padded: 207 pf + 10 betas + 1 vt + 6 zero
constexpr int kNT  = 1296;        // n-tiles of 16 (N_pad = 20736)
constexpr int kNP  = kNT * 16;    // 20736
constexpr int kVC  = 862;         // v-chunk for k_js part (8 chunks)

constexpr int kJsBlocks = kJ * 8;         // 192
constexpr int kPbBlocks = kNP / 64;       // 324
constexpr int kJB  = 4;                   // batches per k_jfv block
constexpr int kLbsTB = 8;                 // batches per k_lbs block
constexpr int kCH  = 384;                 // k_jfv Jh chunk length (18 chunks)

// Output layout (flat concat, FP32 elements)
constexpr size_t O_VERTS  = 0;
constexpr size_t O_JOINTS = (size_t)kB * kV * 3;              // 21166080
constexpr size_t O_ROT    = O_JOINTS + (size_t)kB * kJ * 3;   // 21239808
constexpr size_t O_JFV    = O_ROT + (size_t)kB * kJ * 9;      // 21460992

// Workspace layout (fp32 element offsets).  End = 2,977,792 floats = 11.91 MB.
// (r8 lesson: bswz = 1296*7*512 ushorts = 2,322,432 FLOATS; offsets checked.)
constexpr size_t WS_JSP  = 0;                         // 6336 floats
constexpr size_t WS_ROOT = 8192;                      // kB*3 (pad)
constexpr size_t WS_ABHI = 16384;                     // 1024*512 ushort = 262144 floats
constexpr size_t WS_ABLO = WS_ABHI + 262144;          // 278528
constexpr size_t WS_ASWZ = WS_ABLO + 262144;          // 540672: 1024*224 ushort = 114688 floats
constexpr size_t WS_BSWZ = WS_ASWZ + 114688;          // 655360: 2322432 floats

typedef __attribute__((ext_vector_type(8))) short short8;
typedef __attribute__((ext_vector_type(4))) float float4v;

__device__ __forceinline__ unsigned short f2bf(float f) {
    unsigned u = __float_as_uint(f);
    unsigned r = (u + 0x7FFFu + ((u >> 16) & 1u)) >> 16;  // RNE
    return (unsigned short)r;
}
__device__ __forceinline__ float bf2f(unsigned short h) {
    return __uint_as_float((unsigned)h << 16);
}

// inline classifier: amb0 is lbs_weights iff its first 24 floats sum to ~1.
__device__ __forceinline__ bool amb0_is_weights(const float* __restrict__ amb0) {
    float s = 0.f;
    #pragma unroll
    for (int i = 0; i < kJ; i++) s += amb0[i];
    return fabsf(s - 1.0f) < 0.5f;
}

// swizzled-A element index for (batch b, k-row k); matches k_gemm's read.
__device__ __forceinline__ size_t a_idx(int mtile, int minr, int k) {
    int kt = k >> 5, quad = (k >> 3) & 3, kin = k & 7;
    return ((size_t)(mtile * 7 + kt)) * 512 + (size_t)(quad * 128 + minr * 8 + kin);
}

// ---------------------------------------------------------------------------
// k_sfb: fused front-end (r7-verified body: js + prep_b only).
// ---------------------------------------------------------------------------
__global__ __launch_bounds__(256) void k_sfb(
    const float* __restrict__ amb0,
    const float* __restrict__ amb1,
    const float* __restrict__ sd,
    const float* __restrict__ vt,
    const float* __restrict__ pd,
    float* __restrict__ partial,
    unsigned short* __restrict__ bswz)
{
    __shared__ unsigned short lds[kKP][68];
    __shared__ float red[4][33];

    int t = threadIdx.x;

    if (blockIdx.x < kJsBlocks) {
        // ----- js part -----
        const float* Jreg = amb0_is_weights(amb0) ? amb1 : amb0;
        int j = blockIdx.x >> 3;
        int c = blockIdx.x & 7;
        int lane = t & 63;
        int wave = t >> 6;

        float acc[33];
        #pragma unroll
        for (int i = 0; i < 33; i++) acc[i] = 0.f;

        int vend = min(kVC * (c + 1), kV);
        for (int v = kVC * c + t; v < vend; v += 256) {
            float w = Jreg[j * kV + v];
            const float* sdp = sd + (size_t)v * 30;
            #pragma unroll
            for (int k = 0; k < 3; k++) {
                #pragma unroll
                for (int l = 0; l < kNB; l++)
                    acc[k * 11 + l] += w * sdp[k * 10 + l];
                acc[k * 11 + 10] += w * vt[v * 3 + k];
            }
        }
        #pragma unroll
        for (int off = 32; off > 0; off >>= 1) {
            #pragma unroll
            for (int i = 0; i < 33; i++)
                acc[i] += __shfl_down(acc[i], off, 64);
        }
        if (lane == 0) {
            #pragma unroll
            for (int i = 0; i < 33; i++) red[wave][i] = acc[i];
        }
        __syncthreads();
        if (t < 33) {
            float s = red[0][t] + red[1][t] + red[2][t] + red[3][t];
            partial[((size_t)j * 8 + c) * 33 + t] = s;
        }
    } else {
        // ----- prep_b part -----
        int g = blockIdx.x - kJsBlocks;
        int n0 = g * 64;

        for (int kbase = 0; kbase < kKP; kbase += 4) {
            int k = kbase + (t >> 6);
            int nl = t & 63;
            int n = n0 + nl;
            float val = 0.f;
            if (n < kN) {
                if (k < kP)                 val = pd[(size_t)k * kN + n];
                else if (k < kP + kNB)      val = sd[(size_t)n * kNB + (k - kP)];
                else if (k == kP + kNB)     val = vt[n];
            }
            lds[k][nl] = f2bf(val);
        }
        __syncthreads();

        #pragma unroll 1
        for (int tt = 0; tt < 4; tt++) {
            int ntile = g * 4 + tt;
            #pragma unroll 1
            for (int kt = 0; kt < 7; kt++) {
                size_t base = ((size_t)ntile * 7 + kt) * 512;
                #pragma unroll
                for (int u = 0; u < 2; u++) {
                    int e = t * 2 + u;
                    int quad = e >> 7, rem = e & 127;
                    int nin = rem >> 3, kin = rem & 7;
                    int k = kt * 32 + quad * 8 + kin;
                    bswz[base + e] = lds[k][tt * 16 + nin];
                }
            }
        }
    }
}

// ---------------------------------------------------------------------------
// k_pose: per-batch rodrigues + FK chain + A matrices.
// Emits the per-batch bf16 hi/lo A_flat fragment (MFMA B-operand:
// lane l holds A_flat[j=(l>>4)*8+e][m=l&15]).
// ---------------------------------------------------------------------------
__global__ __launch_bounds__(64) void k_pose(
    const float* __restrict__ pose,
    const float* __restrict__ betas,
    const float* __restrict__ gor,
    const float* __restrict__ jsp,
    float* __restrict__ wsRoot,
    unsigned short* __restrict__ aswz,
    unsigned short* __restrict__ abhi,
    unsigned short* __restrict__ ablo,
    float* __restrict__ out)
{
    __shared__ float Rsh[kJ][9];
    __shared__ float Jr[kJ][3];
    __shared__ float G[kJ][12];
    __shared__ float Ash[kJ][12];

    int b = blockIdx.x;
    int t = threadIdx.x;
    int mtile = b >> 4, minr = b & 15;

    if (t < kJ) {
        float rx, ry, rz;
        if (t == 0) {
            rx = gor[b * 3 + 0]; ry = gor[b * 3 + 1]; rz = gor[b * 3 + 2];
        } else {
            int o = b * 69 + (t - 1) * 3;
            rx = pose[o]; ry = pose[o + 1]; rz = pose[o + 2];
        }
        float ex = rx + 1e-8f, ey = ry + 1e-8f, ez = rz + 1e-8f;
        float ang = sqrtf(ex * ex + ey * ey + ez * ez);
        float x = rx / ang, y = ry / ang, z = rz / ang;
        float s = sinf(ang), c = cosf(ang), oc = 1.0f - c;
        float r[9];
        r[0] = 1.0f - oc * (y * y + z * z);
        r[1] = -s * z + oc * (x * y);
        r[2] =  s * y + oc * (x * z);
        r[3] =  s * z + oc * (x * y);
        r[4] = 1.0f - oc * (x * x + z * z);
        r[5] = -s * x + oc * (y * z);
        r[6] = -s * y + oc * (x * z);
        r[7] =  s * x + oc * (y * z);
        r[8] = 1.0f - oc * (x * x + y * y);
        #pragma unroll
        for (int i = 0; i < 9; i++) Rsh[t][i] = r[i];
        float* ro = out + O_ROT + (size_t)b * (kJ * 9) + (size_t)t * 9;
        #pragma unroll
        for (int i = 0; i < 9; i++) ro[i] = r[i];
        if (t >= 1) {
            #pragma unroll
            for (int i = 0; i < 9; i++) {
                int k = (t - 1) * 9 + i;
                float val = r[i] - ((i == 0 || i == 4 || i == 8) ? 1.0f : 0.0f);
                aswz[a_idx(mtile, minr, k)] = f2bf(val);
            }
        }
        // Jr = (reduced js partials) dot [betas | 1]
        float bt[kNB];
        #pragma unroll
        for (int l = 0; l < kNB; l++) bt[l] = betas[b * kNB + l];
        #pragma unroll
        for (int k2 = 0; k2 < 3; k2++) {
            float row[11];
            #pragma unroll
            for (int i = 0; i < 11; i++) row[i] = 0.f;
            #pragma unroll
            for (int c8 = 0; c8 < 8; c8++) {
                const float* pp = jsp + ((size_t)t * 8 + c8) * 33 + k2 * 11;
                #pragma unroll
                for (int i = 0; i < 11; i++) row[i] += pp[i];
            }
            float acc = row[10];
            #pragma unroll
            for (int l = 0; l < kNB; l++) acc += bt[l] * row[l];
            Jr[t][k2] = acc;
        }
    } else if (t < 41 + kJ) {
        int idx = t - kJ;
        if (idx < 17) {
            int k = kP + idx;
            float val = 0.f;
            if (idx < kNB)          val = betas[b * kNB + idx];
            else if (k == kP + kNB) val = 1.0f;
            aswz[a_idx(mtile, minr, k)] = f2bf(val);
        }
    }
    __syncthreads();

    if (t == 0) {
        const int par[kJ] = {-1,0,0,0,1,2,3,4,5,6,7,8,9,9,9,12,13,14,16,17,18,19,20,21};
        #pragma unroll
        for (int m = 0; m < 3; m++) {
            #pragma unroll
            for (int n = 0; n < 3; n++) G[0][m * 4 + n] = Rsh[0][m * 3 + n];
            G[0][m * 4 + 3] = Jr[0][m];
        }
        for (int i = 1; i < kJ; i++) {
            int p = par[i];
            float rel[3];
            #pragma unroll
            for (int k = 0; k < 3; k++) rel[k] = Jr[i][k] - Jr[p][k];
            #pragma unroll
            for (int m = 0; m < 3; m++) {
                float g0 = G[p][m * 4 + 0], g1 = G[p][m * 4 + 1], g2 = G[p][m * 4 + 2];
                #pragma unroll
                for (int n = 0; n < 3; n++) {
                    G[i][m * 4 + n] = g0 * Rsh[i][0 * 3 + n]
                                    + g1 * Rsh[i][1 * 3 + n]
                                    + g2 * Rsh[i][2 * 3 + n];
                }
                G[i][m * 4 + 3] = g0 * rel[0] + g1 * rel[1] + g2 * rel[2]
                                + G[p][m * 4 + 3];
            }
        }
    }
    __syncthreads();

    if (t < kJ) {
        float* jo = out + O_JOINTS + (size_t)b * (kJ * 3) + (size_t)t * 3;
        #pragma unroll
        for (int m = 0; m < 3; m++) {
            float g0 = G[t][m * 4 + 0], g1 = G[t][m * 4 + 1], g2 = G[t][m * 4 + 2];
            float tr = G[t][m * 4 + 3]
                     - (g0 * Jr[t][0] + g1 * Jr[t][1] + g2 * Jr[t][2]);
            Ash[t][m * 4 + 0] = g0;
            Ash[t][m * 4 + 1] = g1;
            Ash[t][m * 4 + 2] = g2;
            Ash[t][m * 4 + 3] = tr;
            jo[m] = G[t][m * 4 + 3] - G[0][m * 4 + 3];
        }
        if (t == 0) {
            #pragma unroll
            for (int k = 0; k < 3; k++) wsRoot[b * 3 + k] = G[0][k * 4 + 3];
        }
    }
    __syncthreads();

    // bf16 hi/lo B-operand fragment for k_lbs MFMA
    {
        short8 h8, l8;
        #pragma unroll
        for (int e = 0; e < 8; e++) {
            int j = (t >> 4) * 8 + e;
            int m = t & 15;
            float val = (j < kJ && m < 12) ? Ash[j][m] : 0.f;
            unsigned short h = f2bf(val);
            h8[e] = (short)h;
            l8[e] = (short)f2bf(val - bf2f(h));
        }
        *(short8*)(abhi + (size_t)b * 512 + t * 8) = h8;
        *(short8*)(ablo + (size_t)b * 512 + t * 8) = l8;
    }
}

// ---------------------------------------------------------------------------
// k_gemm: v_posed[b][n] = A(1024x224) @ B(224x20670) -> out[O_VERTS] (fp32).
// ---------------------------------------------------------------------------
__global__ __launch_bounds__(256) void k_gemm(
    const unsigned short* __restrict__ A,
    const unsigned short* __restrict__ B,
    float* __restrict__ out)
{
    int tid = threadIdx.x;
    int lane = tid & 63;
    int wid = tid >> 6;
    int m0t = blockIdx.y * 8 + (wid >> 1) * 4;
    int n0t = blockIdx.x * 8 + (wid & 1) * 4;

    float4v acc[4][4];
    #pragma unroll
    for (int i = 0; i < 4; i++)
        #pragma unroll
        for (int j = 0; j < 4; j++)
            acc[i][j] = (float4v){0.f, 0.f, 0.f, 0.f};

    #pragma unroll
    for (int kt = 0; kt < 7; kt++) {
        short8 a[4], b[4];
        #pragma unroll
        for (int i = 0; i < 4; i++)
            a[i] = *(const short8*)(A + ((size_t)(m0t + i) * 7 + kt) * 512 + lane * 8);
        #pragma unroll
        for (int j = 0; j < 4; j++)
            b[j] = *(const short8*)(B + ((size_t)(n0t + j) * 7 + kt) * 512 + lane * 8);
        #pragma unroll
        for (int i = 0; i < 4; i++)
            #pragma unroll
            for (int j = 0; j < 4; j++)
                acc[i][j] = __builtin_amdgcn_mfma_f32_16x16x32_bf16(
                    a[i], b[j], acc[i][j], 0, 0, 0);
    }

    int rbase = (lane >> 4) * 4;
    int col = lane & 15;
    #pragma unroll
    for (int i = 0; i < 4; i++) {
        #pragma unroll
        for (int j = 0; j < 4; j++) {
            int n = (n0t + j) * 16 + col;
            if (n < kN) {
                #pragma unroll
                for (int reg = 0; reg < 4; reg++) {
                    int brow = (m0t + i) * 16 + rbase + reg;
                    out[O_VERTS + (size_t)brow * kN + n] = acc[i][j][reg];
                }
            }
        }
    }
}

// ---------------------------------------------------------------------------
// k_lbs (MFMA): Tv(256v x 12) = W_tile @ A_flat on matrix cores, hi/lo bf16
// split (3 MFMAs; dropped Wlo@Alo <= 2^-18 rel).  W fragments in-register.
// (r9-verified: dropped out of top-5.)
// ---------------------------------------------------------------------------
__global__ __launch_bounds__(256) void k_lbs(
    const float* __restrict__ amb0,
    const float* __restrict__ amb1,
    const unsigned short* __restrict__ abhi,
    const unsigned short* __restrict__ ablo,
    const float* __restrict__ wsRoot,
    float* __restrict__ out)
{
    const float* W = amb0_is_weights(amb0) ? amb0 : amb1;
    __shared__ float ldsT[256 * 13];

    int t = threadIdx.x;
    int lane = t & 63, w = t >> 6;
    int vb = blockIdx.x;            // 0..26
    int b0 = blockIdx.y * kLbsTB;
    int chunk = lane >> 4;          // k-slice 0..3 (3 = pad)

    short8 wh[4], wl[4];
    #pragma unroll
    for (int i = 0; i < 4; i++) {
        int row = vb * 256 + (w * 4 + i) * 16 + (lane & 15);
        float vals[8];
        if (chunk < 3 && row < kV) {
            const float4v* p = (const float4v*)(W + (size_t)row * kJ + chunk * 8);
            float4v x0 = p[0], x1 = p[1];
            vals[0] = x0[0]; vals[1] = x0[1]; vals[2] = x0[2]; vals[3] = x0[3];
            vals[4] = x1[0]; vals[5] = x1[1]; vals[6] = x1[2]; vals[7] = x1[3];
        } else {
            #pragma unroll
            for (int e = 0; e < 8; e++) vals[e] = 0.f;
        }
        #pragma unroll
        for (int e = 0; e < 8; e++) {
            unsigned short h = f2bf(vals[e]);
            wh[i][e] = (short)h;
            wl[i][e] = (short)f2bf(vals[e] - bf2f(h));
        }
    }

    int v = vb * 256 + t;
    bool act = (v < kV);
    int crow = (lane >> 4) * 4;
    int ccol = lane & 15;

    #pragma unroll 1
    for (int tb = 0; tb < kLbsTB; tb++) {
        int b = b0 + tb;
        short8 ah = *(const short8*)(abhi + (size_t)b * 512 + lane * 8);
        short8 al = *(const short8*)(ablo + (size_t)b * 512 + lane * 8);

        #pragma unroll
        for (int i = 0; i < 4; i++) {
            float4v acc = (float4v){0.f, 0.f, 0.f, 0.f};
            acc = __builtin_amdgcn_mfma_f32_16x16x32_bf16(wl[i], ah, acc, 0, 0, 0);
            acc = __builtin_amdgcn_mfma_f32_16x16x32_bf16(wh[i], al, acc, 0, 0, 0);
            acc = __builtin_amdgcn_mfma_f32_16x16x32_bf16(wh[i], ah, acc, 0, 0, 0);
            if (ccol < 12) {
                int base = (w * 4 + i) * 16 * 13;
                #pragma unroll
                for (int reg = 0; reg < 4; reg++)
                    ldsT[base + (crow + reg) * 13 + ccol] = acc[reg];
            }
        }
        __syncthreads();

        {
            const float* T = &ldsT[t * 13];
            float r0 = wsRoot[(size_t)b * 3 + 0];
            float r1 = wsRoot[(size_t)b * 3 + 1];
            float r2 = wsRoot[(size_t)b * 3 + 2];
            if (act) {
                float* op = out + O_VERTS + ((size_t)b * kV + v) * 3;
                float x = op[0], y = op[1], z = op[2];
                float o0 = T[0] * x + T[1] * y + T[2]  * z + T[3]  - r0;
                float o1 = T[4] * x + T[5] * y + T[6]  * z + T[7]  - r1;
                float o2 = T[8] * x + T[9] * y + T[10] * z + T[11] - r2;
                op[0] = o0; op[1] = o1; op[2] = o2;
            }
        }
        __syncthreads();
    }
}

// ---------------------------------------------------------------------------
// k_jfv v2: jfv[b0..b0+3] = Jh @ verts, root17 folded in.
// r9 counters: 75us, VALUBusy 33%, ~19.5 TB/s L2 -> L2-BW-bound on redundant
// reads (each of 16 waves streamed all 4 batches' verts = 16x amplification;
// acc1 FMAs wasted on 15/16 waves).  New decomposition: wave w = (batch w&3,
// row-group w>>2): rows {g,g+4,g+8,g+12} (+16 for g==0), ONE batch's verts
// per wave (4x amp).  Jh chunk (17 x 384) LDS-cached, double-buffered, read
// once per block from L2.  One barrier per chunk; next-chunk load overlaps
// compute.  LDS 53 KB; ~40 VGPR; grid 256 x 1024 thr.
// ---------------------------------------------------------------------------
__global__ __launch_bounds__(1024) void k_jfv(
    const float* __restrict__ Jh,
    const float* __restrict__ verts,
    float* __restrict__ out)
{
    __shared__ float jsh[2][kH][kCH];
    __shared__ float fin[kJB][52];

    int b0 = blockIdx.x * kJB;
    int t = threadIdx.x;
    int wave = t >> 6, lane = t & 63;
    int bb = wave & 3;
    int g  = wave >> 2;             // row-group 0..3
    bool has5 = (g == 0);           // g==0 also handles row 16

    const float* vbase = verts + (size_t)(b0 + bb) * kV * 3;

    float acc[5][3];
    #pragma unroll
    for (int rr = 0; rr < 5; rr++)
        #pragma unroll
        for (int k = 0; k < 3; k++) acc[rr][k] = 0.f;

    constexpr int nc = (kV + kCH - 1) / kCH;   // 18

    // chunk 0 load
    for (int e = t; e < kH * kCH; e += 1024) {
        int r = e / kCH, i = e - r * kCH;
        jsh[0][r][i] = (i < kV) ? Jh[(size_t)r * kV + i] : 0.f;
    }
    __syncthreads();

    #pragma unroll 1
    for (int c = 0; c < nc; c++) {
        int cur = c & 1;
        if (c + 1 < nc) {
            int v0n = (c + 1) * kCH;
            for (int e = t; e < kH * kCH; e += 1024) {
                int r = e / kCH, i = e - r * kCH;
                int v = v0n + i;
                jsh[cur ^ 1][r][i] = (v < kV) ? Jh[(size_t)r * kV + v] : 0.f;
            }
        }
        int v0 = c * kCH;
        int chlen = min(kCH, kV - v0);
        for (int vi = lane; vi < chlen; vi += 64) {
            const float* vp = vbase + (size_t)(v0 + vi) * 3;
            float vx = vp[0], vy = vp[1], vz = vp[2];
            #pragma unroll
            for (int rr = 0; rr < 4; rr++) {
                float wj = jsh[cur][g + rr * 4][vi];
                acc[rr][0] += wj * vx;
                acc[rr][1] += wj * vy;
                acc[rr][2] += wj * vz;
            }
            if (has5) {
                float wj = jsh[cur][16][vi];
                acc[4][0] += wj * vx;
                acc[4][1] += wj * vy;
                acc[4][2] += wj * vz;
            }
        }
        __syncthreads();
    }

    #pragma unroll
    for (int off = 32; off > 0; off >>= 1) {
        #pragma unroll
        for (int rr = 0; rr < 5; rr++)
            #pragma unroll
            for (int k = 0; k < 3; k++)
                acc[rr][k] += __shfl_down(acc[rr][k], off, 64);
    }
    if (lane == 0) {
        #pragma unroll
        for (int rr = 0; rr < 4; rr++)
            #pragma unroll
            for (int k = 0; k < 3; k++)
                fin[bb][(g + rr * 4) * 3 + k] = acc[rr][k];
        if (has5) {
            #pragma unroll
            for (int k = 0; k < 3; k++)
                fin[bb][48 + k] = acc[4][k];
        }
    }
    __syncthreads();
    if (t < kJB * 51) {
        int b2 = t / 51, i = t - b2 * 51;
        // verts already root-subtracted; subtracting the per-axis j'=0 sums
        // reproduces jfv - root17 exactly (Jh rows sum to 1)
        out[O_JFV + (size_t)(b0 + b2) * 51 + i] = fin[b2][i] - fin[b2][i % 3];
    }
}

extern "C" void kernel_launch(void* const* d_in, const int* in_sizes, int n_in,
                              void* d_out, int out_size, void* d_ws, size_t ws_size,
                              hipStream_t stream) {
    const float *pose = nullptr, *betas = nullptr, *gor = nullptr, *vt = nullptr,
                *sd = nullptr, *pd = nullptr, *Jh = nullptr;
    const float *amb0 = nullptr, *amb1 = nullptr;
    for (int i = 0; i < n_in; i++) {
        const float* p = (const float*)d_in[i];
        switch (in_sizes[i]) {
            case 70656:   pose  = p; break;
            case 10240:   betas = p; break;
            case 3072:    gor   = p; break;
            case 20670:   vt    = p; break;
            case 206700:  sd    = p; break;
            case 4278690: pd    = p; break;
            case 117130:  Jh    = p; break;
            case 165360:  if (!amb0) amb0 = p; else amb1 = p; break;
            default: break;
        }
    }

    float* ws = (float*)d_ws;
    float* jsp     = ws + WS_JSP;
    float* wsRoot  = ws + WS_ROOT;
    unsigned short* abhi = (unsigned short*)(ws + WS_ABHI);
    unsigned short* ablo = (unsigned short*)(ws + WS_ABLO);
    unsigned short* aswz = (unsigned short*)(ws + WS_ASWZ);
    unsigned short* bswz = (unsigned short*)(ws + WS_BSWZ);

    float* out = (float*)d_out;

    k_sfb  <<<dim3(kJsBlocks + kPbBlocks), dim3(256), 0, stream>>>(
        amb0, amb1, sd, vt, pd, jsp, bswz);
    k_pose <<<dim3(kB),                 dim3(64),  0, stream>>>(
        pose, betas, gor, jsp, wsRoot, aswz, abhi, ablo, out);
    k_gemm <<<dim3(kNT / 8, kB / 128),  dim3(256), 0, stream>>>(aswz, bswz, out);
    k_lbs  <<<dim3(27, kB / kLbsTB),    dim3(256), 0, stream>>>(
        amb0, amb1, abhi, ablo, wsRoot, out);
    k_jfv  <<<dim3(kB / kJB),           dim3(1024), 0, stream>>>(
        Jh, out + O_VERTS, out);
}

// Round 11
// 258.603 us; speedup vs baseline: 1.1696x; 1.1696x over previous
//
#include <hip/hip_runtime.h>
#include <hip/hip_bf16.h>

// Problem constants
constexpr int kB  = 1024;
constexpr int kV  = 6890;
constexpr int kJ  = 24;
constexpr int kNB = 10;
constexpr int kP  = 207;   // 23*9
constexpr int kH  = 17;

constexpr int kN   = kV * 3;      // 20670
constexpr int kKP  = 224;         // K padded: 207 pf + 10 betas + 1 vt + 6 zero
constexpr int kNT  = 1296;        // n-tiles of 16 (N_pad = 20736)
constexpr int kNP  = kNT * 16;    // 20736
constexpr int kVC  = 862;         // v-chunk for k_js part (8 chunks)

constexpr int kJsBlocks = kJ * 8;         // 192
constexpr int kPbBlocks = kNP / 64;       // 324
constexpr int kJB  = 4;                   // batches per k_jfv block
constexpr int kLbsTB = 8;                 // batches per k_lbs block
constexpr int kSL  = 1723;                // k_jfv verts slice (4 slices: 3x1723+1721)

// Output layout (flat concat, FP32 elements)
constexpr size_t O_VERTS  = 0;
constexpr size_t O_JOINTS = (size_t)kB * kV * 3;              // 21166080
constexpr size_t O_ROT    = O_JOINTS + (size_t)kB * kJ * 3;   // 21239808
constexpr size_t O_JFV    = O_ROT + (size_t)kB * kJ * 9;      // 21460992

// Workspace layout (fp32 element offsets).  End = 2,977,792 floats = 11.91 MB.
// (r8 lesson: bswz = 1296*7*512 ushorts = 2,322,432 FLOATS; offsets checked.)
constexpr size_t WS_JSP  = 0;                         // 6336 floats
constexpr size_t WS_ROOT = 8192;                      // kB*3 (pad)
constexpr size_t WS_ABHI = 16384;                     // 1024*512 ushort = 262144 floats
constexpr size_t WS_ABLO = WS_ABHI + 262144;          // 278528
constexpr size_t WS_ASWZ = WS_ABLO + 262144;          // 540672: 1024*224 ushort = 114688 floats
constexpr size_t WS_BSWZ = WS_ASWZ + 114688;          // 655360: 2322432 floats

typedef __attribute__((ext_vector_type(8))) short short8;
typedef __attribute__((ext_vector_type(4))) float float4v;

__device__ __forceinline__ unsigned short f2bf(float f) {
    unsigned u = __float_as_uint(f);
    unsigned r = (u + 0x7FFFu + ((u >> 16) & 1u)) >> 16;  // RNE
    return (unsigned short)r;
}
__device__ __forceinline__ float bf2f(unsigned short h) {
    return __uint_as_float((unsigned)h << 16);
}

// inline classifier: amb0 is lbs_weights iff its first 24 floats sum to ~1.
__device__ __forceinline__ bool amb0_is_weights(const float* __restrict__ amb0) {
    float s = 0.f;
    #pragma unroll
    for (int i = 0; i < kJ; i++) s += amb0[i];
    return fabsf(s - 1.0f) < 0.5f;
}

// swizzled-A element index for (batch b, k-row k); matches k_gemm's read.
__device__ __forceinline__ size_t a_idx(int mtile, int minr, int k) {
    int kt = k >> 5, quad = (k >> 3) & 3, kin = k & 7;
    return ((size_t)(mtile * 7 + kt)) * 512 + (size_t)(quad * 128 + minr * 8 + kin);
}

// ---------------------------------------------------------------------------
// k_sfb: fused front-end (r7-verified body: js + prep_b only).
// ---------------------------------------------------------------------------
__global__ __launch_bounds__(256) void k_sfb(
    const float* __restrict__ amb0,
    const float* __restrict__ amb1,
    const float* __restrict__ sd,
    const float* __restrict__ vt,
    const float* __restrict__ pd,
    float* __restrict__ partial,
    unsigned short* __restrict__ bswz)
{
    __shared__ unsigned short lds[kKP][68];
    __shared__ float red[4][33];

    int t = threadIdx.x;

    if (blockIdx.x < kJsBlocks) {
        // ----- js part -----
        const float* Jreg = amb0_is_weights(amb0) ? amb1 : amb0;
        int j = blockIdx.x >> 3;
        int c = blockIdx.x & 7;
        int lane = t & 63;
        int wave = t >> 6;

        float acc[33];
        #pragma unroll
        for (int i = 0; i < 33; i++) acc[i] = 0.f;

        int vend = min(kVC * (c + 1), kV);
        for (int v = kVC * c + t; v < vend; v += 256) {
            float w = Jreg[j * kV + v];
            const float* sdp = sd + (size_t)v * 30;
            #pragma unroll
            for (int k = 0; k < 3; k++) {
                #pragma unroll
                for (int l = 0; l < kNB; l++)
                    acc[k * 11 + l] += w * sdp[k * 10 + l];
                acc[k * 11 + 10] += w * vt[v * 3 + k];
            }
        }
        #pragma unroll
        for (int off = 32; off > 0; off >>= 1) {
            #pragma unroll
            for (int i = 0; i < 33; i++)
                acc[i] += __shfl_down(acc[i], off, 64);
        }
        if (lane == 0) {
            #pragma unroll
            for (int i = 0; i < 33; i++) red[wave][i] = acc[i];
        }
        __syncthreads();
        if (t < 33) {
            float s = red[0][t] + red[1][t] + red[2][t] + red[3][t];
            partial[((size_t)j * 8 + c) * 33 + t] = s;
        }
    } else {
        // ----- prep_b part -----
        int g = blockIdx.x - kJsBlocks;
        int n0 = g * 64;

        for (int kbase = 0; kbase < kKP; kbase += 4) {
            int k = kbase + (t >> 6);
            int nl = t & 63;
            int n = n0 + nl;
            float val = 0.f;
            if (n < kN) {
                if (k < kP)                 val = pd[(size_t)k * kN + n];
                else if (k < kP + kNB)      val = sd[(size_t)n * kNB + (k - kP)];
                else if (k == kP + kNB)     val = vt[n];
            }
            lds[k][nl] = f2bf(val);
        }
        __syncthreads();

        #pragma unroll 1
        for (int tt = 0; tt < 4; tt++) {
            int ntile = g * 4 + tt;
            #pragma unroll 1
            for (int kt = 0; kt < 7; kt++) {
                size_t base = ((size_t)ntile * 7 + kt) * 512;
                #pragma unroll
                for (int u = 0; u < 2; u++) {
                    int e = t * 2 + u;
                    int quad = e >> 7, rem = e & 127;
                    int nin = rem >> 3, kin = rem & 7;
                    int k = kt * 32 + quad * 8 + kin;
                    bswz[base + e] = lds[k][tt * 16 + nin];
                }
            }
        }
    }
}

// ---------------------------------------------------------------------------
// k_pose: per-batch rodrigues + FK chain + A matrices.
// Emits the per-batch bf16 hi/lo A_flat fragment (MFMA B-operand:
// lane l holds A_flat[j=(l>>4)*8+e][m=l&15]).
// ---------------------------------------------------------------------------
__global__ __launch_bounds__(64) void k_pose(
    const float* __restrict__ pose,
    const float* __restrict__ betas,
    const float* __restrict__ gor,
    const float* __restrict__ jsp,
    float* __restrict__ wsRoot,
    unsigned short* __restrict__ aswz,
    unsigned short* __restrict__ abhi,
    unsigned short* __restrict__ ablo,
    float* __restrict__ out)
{
    __shared__ float Rsh[kJ][9];
    __shared__ float Jr[kJ][3];
    __shared__ float G[kJ][12];
    __shared__ float Ash[kJ][12];

    int b = blockIdx.x;
    int t = threadIdx.x;
    int mtile = b >> 4, minr = b & 15;

    if (t < kJ) {
        float rx, ry, rz;
        if (t == 0) {
            rx = gor[b * 3 + 0]; ry = gor[b * 3 + 1]; rz = gor[b * 3 + 2];
        } else {
            int o = b * 69 + (t - 1) * 3;
            rx = pose[o]; ry = pose[o + 1]; rz = pose[o + 2];
        }
        float ex = rx + 1e-8f, ey = ry + 1e-8f, ez = rz + 1e-8f;
        float ang = sqrtf(ex * ex + ey * ey + ez * ez);
        float x = rx / ang, y = ry / ang, z = rz / ang;
        float s = sinf(ang), c = cosf(ang), oc = 1.0f - c;
        float r[9];
        r[0] = 1.0f - oc * (y * y + z * z);
        r[1] = -s * z + oc * (x * y);
        r[2] =  s * y + oc * (x * z);
        r[3] =  s * z + oc * (x * y);
        r[4] = 1.0f - oc * (x * x + z * z);
        r[5] = -s * x + oc * (y * z);
        r[6] = -s * y + oc * (x * z);
        r[7] =  s * x + oc * (y * z);
        r[8] = 1.0f - oc * (x * x + y * y);
        #pragma unroll
        for (int i = 0; i < 9; i++) Rsh[t][i] = r[i];
        float* ro = out + O_ROT + (size_t)b * (kJ * 9) + (size_t)t * 9;
        #pragma unroll
        for (int i = 0; i < 9; i++) ro[i] = r[i];
        if (t >= 1) {
            #pragma unroll
            for (int i = 0; i < 9; i++) {
                int k = (t - 1) * 9 + i;
                float val = r[i] - ((i == 0 || i == 4 || i == 8) ? 1.0f : 0.0f);
                aswz[a_idx(mtile, minr, k)] = f2bf(val);
            }
        }
        // Jr = (reduced js partials) dot [betas | 1]
        float bt[kNB];
        #pragma unroll
        for (int l = 0; l < kNB; l++) bt[l] = betas[b * kNB + l];
        #pragma unroll
        for (int k2 = 0; k2 < 3; k2++) {
            float row[11];
            #pragma unroll
            for (int i = 0; i < 11; i++) row[i] = 0.f;
            #pragma unroll
            for (int c8 = 0; c8 < 8; c8++) {
                const float* pp = jsp + ((size_t)t * 8 + c8) * 33 + k2 * 11;
                #pragma unroll
                for (int i = 0; i < 11; i++) row[i] += pp[i];
            }
            float acc = row[10];
            #pragma unroll
            for (int l = 0; l < kNB; l++) acc += bt[l] * row[l];
            Jr[t][k2] = acc;
        }
    } else if (t < 41 + kJ) {
        int idx = t - kJ;
        if (idx < 17) {
            int k = kP + idx;
            float val = 0.f;
            if (idx < kNB)          val = betas[b * kNB + idx];
            else if (k == kP + kNB) val = 1.0f;
            aswz[a_idx(mtile, minr, k)] = f2bf(val);
        }
    }
    __syncthreads();

    if (t == 0) {
        const int par[kJ] = {-1,0,0,0,1,2,3,4,5,6,7,8,9,9,9,12,13,14,16,17,18,19,20,21};
        #pragma unroll
        for (int m = 0; m < 3; m++) {
            #pragma unroll
            for (int n = 0; n < 3; n++) G[0][m * 4 + n] = Rsh[0][m * 3 + n];
            G[0][m * 4 + 3] = Jr[0][m];
        }
        for (int i = 1; i < kJ; i++) {
            int p = par[i];
            float rel[3];
            #pragma unroll
            for (int k = 0; k < 3; k++) rel[k] = Jr[i][k] - Jr[p][k];
            #pragma unroll
            for (int m = 0; m < 3; m++) {
                float g0 = G[p][m * 4 + 0], g1 = G[p][m * 4 + 1], g2 = G[p][m * 4 + 2];
                #pragma unroll
                for (int n = 0; n < 3; n++) {
                    G[i][m * 4 + n] = g0 * Rsh[i][0 * 3 + n]
                                    + g1 * Rsh[i][1 * 3 + n]
                                    + g2 * Rsh[i][2 * 3 + n];
                }
                G[i][m * 4 + 3] = g0 * rel[0] + g1 * rel[1] + g2 * rel[2]
                                + G[p][m * 4 + 3];
            }
        }
    }
    __syncthreads();

    if (t < kJ) {
        float* jo = out + O_JOINTS + (size_t)b * (kJ * 3) + (size_t)t * 3;
        #pragma unroll
        for (int m = 0; m < 3; m++) {
            float g0 = G[t][m * 4 + 0], g1 = G[t][m * 4 + 1], g2 = G[t][m * 4 + 2];
            float tr = G[t][m * 4 + 3]
                     - (g0 * Jr[t][0] + g1 * Jr[t][1] + g2 * Jr[t][2]);
            Ash[t][m * 4 + 0] = g0;
            Ash[t][m * 4 + 1] = g1;
            Ash[t][m * 4 + 2] = g2;
            Ash[t][m * 4 + 3] = tr;
            jo[m] = G[t][m * 4 + 3] - G[0][m * 4 + 3];
        }
        if (t == 0) {
            #pragma unroll
            for (int k = 0; k < 3; k++) wsRoot[b * 3 + k] = G[0][k * 4 + 3];
        }
    }
    __syncthreads();

    // bf16 hi/lo B-operand fragment for k_lbs MFMA
    {
        short8 h8, l8;
        #pragma unroll
        for (int e = 0; e < 8; e++) {
            int j = (t >> 4) * 8 + e;
            int m = t & 15;
            float val = (j < kJ && m < 12) ? Ash[j][m] : 0.f;
            unsigned short h = f2bf(val);
            h8[e] = (short)h;
            l8[e] = (short)f2bf(val - bf2f(h));
        }
        *(short8*)(abhi + (size_t)b * 512 + t * 8) = h8;
        *(short8*)(ablo + (size_t)b * 512 + t * 8) = l8;
    }
}

// ---------------------------------------------------------------------------
// k_gemm: v_posed[b][n] = A(1024x224) @ B(224x20670) -> out[O_VERTS] (fp32).
// ---------------------------------------------------------------------------
__global__ __launch_bounds__(256) void k_gemm(
    const unsigned short* __restrict__ A,
    const unsigned short* __restrict__ B,
    float* __restrict__ out)
{
    int tid = threadIdx.x;
    int lane = tid & 63;
    int wid = tid >> 6;
    int m0t = blockIdx.y * 8 + (wid >> 1) * 4;
    int n0t = blockIdx.x * 8 + (wid & 1) * 4;

    float4v acc[4][4];
    #pragma unroll
    for (int i = 0; i < 4; i++)
        #pragma unroll
        for (int j = 0; j < 4; j++)
            acc[i][j] = (float4v){0.f, 0.f, 0.f, 0.f};

    #pragma unroll
    for (int kt = 0; kt < 7; kt++) {
        short8 a[4], b[4];
        #pragma unroll
        for (int i = 0; i < 4; i++)
            a[i] = *(const short8*)(A + ((size_t)(m0t + i) * 7 + kt) * 512 + lane * 8);
        #pragma unroll
        for (int j = 0; j < 4; j++)
            b[j] = *(const short8*)(B + ((size_t)(n0t + j) * 7 + kt) * 512 + lane * 8);
        #pragma unroll
        for (int i = 0; i < 4; i++)
            #pragma unroll
            for (int j = 0; j < 4; j++)
                acc[i][j] = __builtin_amdgcn_mfma_f32_16x16x32_bf16(
                    a[i], b[j], acc[i][j], 0, 0, 0);
    }

    int rbase = (lane >> 4) * 4;
    int col = lane & 15;
    #pragma unroll
    for (int i = 0; i < 4; i++) {
        #pragma unroll
        for (int j = 0; j < 4; j++) {
            int n = (n0t + j) * 16 + col;
            if (n < kN) {
                #pragma unroll
                for (int reg = 0; reg < 4; reg++) {
                    int brow = (m0t + i) * 16 + rbase + reg;
                    out[O_VERTS + (size_t)brow * kN + n] = acc[i][j][reg];
                }
            }
        }
    }
}

// ---------------------------------------------------------------------------
// k_lbs (MFMA): Tv(256v x 12) = W_tile @ A_flat on matrix cores, hi/lo bf16
// split (3 MFMAs; dropped Wlo@Alo <= 2^-18 rel).  W fragments in-register.
// (r9-verified: dropped out of top-5.)
// ---------------------------------------------------------------------------
__global__ __launch_bounds__(256) void k_lbs(
    const float* __restrict__ amb0,
    const float* __restrict__ amb1,
    const unsigned short* __restrict__ abhi,
    const unsigned short* __restrict__ ablo,
    const float* __restrict__ wsRoot,
    float* __restrict__ out)
{
    const float* W = amb0_is_weights(amb0) ? amb0 : amb1;
    __shared__ float ldsT[256 * 13];

    int t = threadIdx.x;
    int lane = t & 63, w = t >> 6;
    int vb = blockIdx.x;            // 0..26
    int b0 = blockIdx.y * kLbsTB;
    int chunk = lane >> 4;          // k-slice 0..3 (3 = pad)

    short8 wh[4], wl[4];
    #pragma unroll
    for (int i = 0; i < 4; i++) {
        int row = vb * 256 + (w * 4 + i) * 16 + (lane & 15);
        float vals[8];
        if (chunk < 3 && row < kV) {
            const float4v* p = (const float4v*)(W + (size_t)row * kJ + chunk * 8);
            float4v x0 = p[0], x1 = p[1];
            vals[0] = x0[0]; vals[1] = x0[1]; vals[2] = x0[2]; vals[3] = x0[3];
            vals[4] = x1[0]; vals[5] = x1[1]; vals[6] = x1[2]; vals[7] = x1[3];
        } else {
            #pragma unroll
            for (int e = 0; e < 8; e++) vals[e] = 0.f;
        }
        #pragma unroll
        for (int e = 0; e < 8; e++) {
            unsigned short h = f2bf(vals[e]);
            wh[i][e] = (short)h;
            wl[i][e] = (short)f2bf(vals[e] - bf2f(h));
        }
    }

    int v = vb * 256 + t;
    bool act = (v < kV);
    int crow = (lane >> 4) * 4;
    int ccol = lane & 15;

    #pragma unroll 1
    for (int tb = 0; tb < kLbsTB; tb++) {
        int b = b0 + tb;
        short8 ah = *(const short8*)(abhi + (size_t)b * 512 + lane * 8);
        short8 al = *(const short8*)(ablo + (size_t)b * 512 + lane * 8);

        #pragma unroll
        for (int i = 0; i < 4; i++) {
            float4v acc = (float4v){0.f, 0.f, 0.f, 0.f};
            acc = __builtin_amdgcn_mfma_f32_16x16x32_bf16(wl[i], ah, acc, 0, 0, 0);
            acc = __builtin_amdgcn_mfma_f32_16x16x32_bf16(wh[i], al, acc, 0, 0, 0);
            acc = __builtin_amdgcn_mfma_f32_16x16x32_bf16(wh[i], ah, acc, 0, 0, 0);
            if (ccol < 12) {
                int base = (w * 4 + i) * 16 * 13;
                #pragma unroll
                for (int reg = 0; reg < 4; reg++)
                    ldsT[base + (crow + reg) * 13 + ccol] = acc[reg];
            }
        }
        __syncthreads();

        {
            const float* T = &ldsT[t * 13];
            float r0 = wsRoot[(size_t)b * 3 + 0];
            float r1 = wsRoot[(size_t)b * 3 + 1];
            float r2 = wsRoot[(size_t)b * 3 + 2];
            if (act) {
                float* op = out + O_VERTS + ((size_t)b * kV + v) * 3;
                float x = op[0], y = op[1], z = op[2];
                float o0 = T[0] * x + T[1] * y + T[2]  * z + T[3]  - r0;
                float o1 = T[4] * x + T[5] * y + T[6]  * z + T[7]  - r1;
                float o2 = T[8] * x + T[9] * y + T[10] * z + T[11] - r2;
                op[0] = o0; op[1] = o1; op[2] = o2;
            }
        }
        __syncthreads();
    }
}

// ---------------------------------------------------------------------------
// k_jfv v3: jfv[b0..b0+3] = Jh @ verts, root17 folded in.  BARRIER-FREE.
// r10 post-mortem: v2's 18 chunk barriers serialized a 16-wave block (94us,
// VALUBusy 26%).  v1 (75us) was L2-BW-bound on 16x verts amplification.
// v3: wave w = (batch w>>2, verts-slice w&3) with acc[17][3] (51 regs,
// single-batch -- r4's failure was 2x51 at >=112 VGPR).  verts amp 1x,
// Jh amp 4x/block: ~2.2 MB/block vs v1's 5.7 MB.  No mid-loop barriers;
// one final LDS reduce (16x51 -> 4x51).  Grid 256 x 1024 thr.
// ---------------------------------------------------------------------------
__global__ __launch_bounds__(1024) void k_jfv(
    const float* __restrict__ Jh,
    const float* __restrict__ verts,
    float* __restrict__ out)
{
    __shared__ float part[16][kH * 3];

    int b0 = blockIdx.x * kJB;
    int t = threadIdx.x;
    int wave = t >> 6, lane = t & 63;
    int bb = wave >> 2;             // batch 0..3
    int sl = wave & 3;              // verts slice 0..3

    const float* vbase = verts + (size_t)(b0 + bb) * kV * 3;

    float acc[kH][3];
    #pragma unroll
    for (int r = 0; r < kH; r++)
        #pragma unroll
        for (int k = 0; k < 3; k++) acc[r][k] = 0.f;

    int vend = min(kSL * (sl + 1), kV);
    for (int v = kSL * sl + lane; v < vend; v += 64) {
        const float* vp = vbase + (size_t)v * 3;
        float vx = vp[0], vy = vp[1], vz = vp[2];
        #pragma unroll
        for (int r = 0; r < kH; r++) {
            float wj = Jh[(size_t)r * kV + v];
            acc[r][0] += wj * vx;
            acc[r][1] += wj * vy;
            acc[r][2] += wj * vz;
        }
    }

    #pragma unroll
    for (int off = 32; off > 0; off >>= 1) {
        #pragma unroll
        for (int r = 0; r < kH; r++)
            #pragma unroll
            for (int k = 0; k < 3; k++)
                acc[r][k] += __shfl_down(acc[r][k], off, 64);
    }
    if (lane == 0) {
        #pragma unroll
        for (int r = 0; r < kH; r++)
            #pragma unroll
            for (int k = 0; k < 3; k++)
                part[wave][r * 3 + k] = acc[r][k];
    }
    __syncthreads();
    if (t < kJB * (kH * 3)) {
        int b2 = t / (kH * 3), i = t - b2 * (kH * 3);
        float s  = part[b2 * 4 + 0][i] + part[b2 * 4 + 1][i]
                 + part[b2 * 4 + 2][i] + part[b2 * 4 + 3][i];
        int k = i % 3;
        float sk = part[b2 * 4 + 0][k] + part[b2 * 4 + 1][k]
                 + part[b2 * 4 + 2][k] + part[b2 * 4 + 3][k];
        // verts already root-subtracted; subtracting the per-axis j'=0 sums
        // reproduces jfv - root17 exactly (Jh rows sum to 1)
        out[O_JFV + (size_t)(b0 + b2) * 51 + i] = s - sk;
    }
}

extern "C" void kernel_launch(void* const* d_in, const int* in_sizes, int n_in,
                              void* d_out, int out_size, void* d_ws, size_t ws_size,
                              hipStream_t stream) {
    const float *pose = nullptr, *betas = nullptr, *gor = nullptr, *vt = nullptr,
                *sd = nullptr, *pd = nullptr, *Jh = nullptr;
    const float *amb0 = nullptr, *amb1 = nullptr;
    for (int i = 0; i < n_in; i++) {
        const float* p = (const float*)d_in[i];
        switch (in_sizes[i]) {
            case 70656:   pose  = p; break;
            case 10240:   betas = p; break;
            case 3072:    gor   = p; break;
            case 20670:   vt    = p; break;
            case 206700:  sd    = p; break;
            case 4278690: pd    = p; break;
            case 117130:  Jh    = p; break;
            case 165360:  if (!amb0) amb0 = p; else amb1 = p; break;
            default: break;
        }
    }

    float* ws = (float*)d_ws;
    float* jsp     = ws + WS_JSP;
    float* wsRoot  = ws + WS_ROOT;
    unsigned short* abhi = (unsigned short*)(ws + WS_ABHI);
    unsigned short* ablo = (unsigned short*)(ws + WS_ABLO);
    unsigned short* aswz = (unsigned short*)(ws + WS_ASWZ);
    unsigned short* bswz = (unsigned short*)(ws + WS_BSWZ);

    float* out = (float*)d_out;

    k_sfb  <<<dim3(kJsBlocks + kPbBlocks), dim3(256), 0, stream>>>(
        amb0, amb1, sd, vt, pd, jsp, bswz);
    k_pose <<<dim3(kB),                 dim3(64),  0, stream>>>(
        pose, betas, gor, jsp, wsRoot, aswz, abhi, ablo, out);
    k_gemm <<<dim3(kNT / 8, kB / 128),  dim3(256), 0, stream>>>(aswz, bswz, out);
    k_lbs  <<<dim3(27, kB / kLbsTB),    dim3(256), 0, stream>>>(
        amb0, amb1, abhi, ablo, wsRoot, out);
    k_jfv  <<<dim3(kB / kJB),           dim3(1024), 0, stream>>>(
        Jh, out + O_VERTS, out);
}

// Round 12
// 253.297 us; speedup vs baseline: 1.1941x; 1.0209x over previous
//
#include <hip/hip_runtime.h>
#include <hip/hip_bf16.h>

// Problem constants
constexpr int kB  = 1024;
constexpr int kV  = 6890;
constexpr int kJ  = 24;
constexpr int kNB = 10;
constexpr int kP  = 207;   // 23*9
constexpr int kH  = 17;

constexpr int kN   = kV * 3;      // 20670
constexpr int kKP  = 224;         // K padded: 207 pf + 10 betas + 1 vt + 6 zero
constexpr int kNT  = 1296;        // n-tiles of 16 (N_pad = 20736)
constexpr int kNP  = kNT * 16;    // 20736
constexpr int kVC  = 862;         // v-chunk for k_js part (8 chunks)

constexpr int kJsBlocks = kJ * 8;         // 192
constexpr int kPbBlocks = kNP / 64;       // 324
constexpr int kLbsTB = 8;                 // batches per k_lbs block
constexpr int kSL  = 1723;                // k_jfv verts slice (4 slices: 3x1723+1721)
constexpr int kJfvTB = 2;                 // batches per k_jfv block

// Output layout (flat concat, FP32 elements)
constexpr size_t O_VERTS  = 0;
constexpr size_t O_JOINTS = (size_t)kB * kV * 3;              // 21166080
constexpr size_t O_ROT    = O_JOINTS + (size_t)kB * kJ * 3;   // 21239808
constexpr size_t O_JFV    = O_ROT + (size_t)kB * kJ * 9;      // 21460992

// Workspace layout (fp32 element offsets).  End = 2,977,792 floats = 11.91 MB.
// (r8 lesson: bswz = 1296*7*512 ushorts = 2,322,432 FLOATS; offsets checked.)
constexpr size_t WS_JSP  = 0;                         // 6336 floats
constexpr size_t WS_ROOT = 8192;                      // kB*3 (pad)
constexpr size_t WS_ABHI = 16384;                     // 1024*512 ushort = 262144 floats
constexpr size_t WS_ABLO = WS_ABHI + 262144;          // 278528
constexpr size_t WS_ASWZ = WS_ABLO + 262144;          // 540672: 1024*224 ushort = 114688 floats
constexpr size_t WS_BSWZ = WS_ASWZ + 114688;          // 655360: 2322432 floats
// jht (V x 20 padded transpose of Jh, 137,800 floats) OVERLAYS bswz:
// bswz is dead after k_gemm; k_tr writes jht between k_gemm and k_lbs.
constexpr size_t WS_JHT  = WS_BSWZ;

typedef __attribute__((ext_vector_type(8))) short short8;
typedef __attribute__((ext_vector_type(4))) float float4v;

__device__ __forceinline__ unsigned short f2bf(float f) {
    unsigned u = __float_as_uint(f);
    unsigned r = (u + 0x7FFFu + ((u >> 16) & 1u)) >> 16;  // RNE
    return (unsigned short)r;
}
__device__ __forceinline__ float bf2f(unsigned short h) {
    return __uint_as_float((unsigned)h << 16);
}

// inline classifier: amb0 is lbs_weights iff its first 24 floats sum to ~1.
__device__ __forceinline__ bool amb0_is_weights(const float* __restrict__ amb0) {
    float s = 0.f;
    #pragma unroll
    for (int i = 0; i < kJ; i++) s += amb0[i];
    return fabsf(s - 1.0f) < 0.5f;
}

// swizzled-A element index for (batch b, k-row k); matches k_gemm's read.
__device__ __forceinline__ size_t a_idx(int mtile, int minr, int k) {
    int kt = k >> 5, quad = (k >> 3) & 3, kin = k & 7;
    return ((size_t)(mtile * 7 + kt)) * 512 + (size_t)(quad * 128 + minr * 8 + kin);
}

// ---------------------------------------------------------------------------
// k_sfb: fused front-end (r7-verified body: js + prep_b only).
// ---------------------------------------------------------------------------
__global__ __launch_bounds__(256) void k_sfb(
    const float* __restrict__ amb0,
    const float* __restrict__ amb1,
    const float* __restrict__ sd,
    const float* __restrict__ vt,
    const float* __restrict__ pd,
    float* __restrict__ partial,
    unsigned short* __restrict__ bswz)
{
    __shared__ unsigned short lds[kKP][68];
    __shared__ float red[4][33];

    int t = threadIdx.x;

    if (blockIdx.x < kJsBlocks) {
        // ----- js part -----
        const float* Jreg = amb0_is_weights(amb0) ? amb1 : amb0;
        int j = blockIdx.x >> 3;
        int c = blockIdx.x & 7;
        int lane = t & 63;
        int wave = t >> 6;

        float acc[33];
        #pragma unroll
        for (int i = 0; i < 33; i++) acc[i] = 0.f;

        int vend = min(kVC * (c + 1), kV);
        for (int v = kVC * c + t; v < vend; v += 256) {
            float w = Jreg[j * kV + v];
            const float* sdp = sd + (size_t)v * 30;
            #pragma unroll
            for (int k = 0; k < 3; k++) {
                #pragma unroll
                for (int l = 0; l < kNB; l++)
                    acc[k * 11 + l] += w * sdp[k * 10 + l];
                acc[k * 11 + 10] += w * vt[v * 3 + k];
            }
        }
        #pragma unroll
        for (int off = 32; off > 0; off >>= 1) {
            #pragma unroll
            for (int i = 0; i < 33; i++)
                acc[i] += __shfl_down(acc[i], off, 64);
        }
        if (lane == 0) {
            #pragma unroll
            for (int i = 0; i < 33; i++) red[wave][i] = acc[i];
        }
        __syncthreads();
        if (t < 33) {
            float s = red[0][t] + red[1][t] + red[2][t] + red[3][t];
            partial[((size_t)j * 8 + c) * 33 + t] = s;
        }
    } else {
        // ----- prep_b part -----
        int g = blockIdx.x - kJsBlocks;
        int n0 = g * 64;

        for (int kbase = 0; kbase < kKP; kbase += 4) {
            int k = kbase + (t >> 6);
            int nl = t & 63;
            int n = n0 + nl;
            float val = 0.f;
            if (n < kN) {
                if (k < kP)                 val = pd[(size_t)k * kN + n];
                else if (k < kP + kNB)      val = sd[(size_t)n * kNB + (k - kP)];
                else if (k == kP + kNB)     val = vt[n];
            }
            lds[k][nl] = f2bf(val);
        }
        __syncthreads();

        #pragma unroll 1
        for (int tt = 0; tt < 4; tt++) {
            int ntile = g * 4 + tt;
            #pragma unroll 1
            for (int kt = 0; kt < 7; kt++) {
                size_t base = ((size_t)ntile * 7 + kt) * 512;
                #pragma unroll
                for (int u = 0; u < 2; u++) {
                    int e = t * 2 + u;
                    int quad = e >> 7, rem = e & 127;
                    int nin = rem >> 3, kin = rem & 7;
                    int k = kt * 32 + quad * 8 + kin;
                    bswz[base + e] = lds[k][tt * 16 + nin];
                }
            }
        }
    }
}

// ---------------------------------------------------------------------------
// k_pose: per-batch rodrigues + FK chain + A matrices.
// Emits the per-batch bf16 hi/lo A_flat fragment (MFMA B-operand:
// lane l holds A_flat[j=(l>>4)*8+e][m=l&15]).
// ---------------------------------------------------------------------------
__global__ __launch_bounds__(64) void k_pose(
    const float* __restrict__ pose,
    const float* __restrict__ betas,
    const float* __restrict__ gor,
    const float* __restrict__ jsp,
    float* __restrict__ wsRoot,
    unsigned short* __restrict__ aswz,
    unsigned short* __restrict__ abhi,
    unsigned short* __restrict__ ablo,
    float* __restrict__ out)
{
    __shared__ float Rsh[kJ][9];
    __shared__ float Jr[kJ][3];
    __shared__ float G[kJ][12];
    __shared__ float Ash[kJ][12];

    int b = blockIdx.x;
    int t = threadIdx.x;
    int mtile = b >> 4, minr = b & 15;

    if (t < kJ) {
        float rx, ry, rz;
        if (t == 0) {
            rx = gor[b * 3 + 0]; ry = gor[b * 3 + 1]; rz = gor[b * 3 + 2];
        } else {
            int o = b * 69 + (t - 1) * 3;
            rx = pose[o]; ry = pose[o + 1]; rz = pose[o + 2];
        }
        float ex = rx + 1e-8f, ey = ry + 1e-8f, ez = rz + 1e-8f;
        float ang = sqrtf(ex * ex + ey * ey + ez * ez);
        float x = rx / ang, y = ry / ang, z = rz / ang;
        float s = sinf(ang), c = cosf(ang), oc = 1.0f - c;
        float r[9];
        r[0] = 1.0f - oc * (y * y + z * z);
        r[1] = -s * z + oc * (x * y);
        r[2] =  s * y + oc * (x * z);
        r[3] =  s * z + oc * (x * y);
        r[4] = 1.0f - oc * (x * x + z * z);
        r[5] = -s * x + oc * (y * z);
        r[6] = -s * y + oc * (x * z);
        r[7] =  s * x + oc * (y * z);
        r[8] = 1.0f - oc * (x * x + y * y);
        #pragma unroll
        for (int i = 0; i < 9; i++) Rsh[t][i] = r[i];
        float* ro = out + O_ROT + (size_t)b * (kJ * 9) + (size_t)t * 9;
        #pragma unroll
        for (int i = 0; i < 9; i++) ro[i] = r[i];
        if (t >= 1) {
            #pragma unroll
            for (int i = 0; i < 9; i++) {
                int k = (t - 1) * 9 + i;
                float val = r[i] - ((i == 0 || i == 4 || i == 8) ? 1.0f : 0.0f);
                aswz[a_idx(mtile, minr, k)] = f2bf(val);
            }
        }
        // Jr = (reduced js partials) dot [betas | 1]
        float bt[kNB];
        #pragma unroll
        for (int l = 0; l < kNB; l++) bt[l] = betas[b * kNB + l];
        #pragma unroll
        for (int k2 = 0; k2 < 3; k2++) {
            float row[11];
            #pragma unroll
            for (int i = 0; i < 11; i++) row[i] = 0.f;
            #pragma unroll
            for (int c8 = 0; c8 < 8; c8++) {
                const float* pp = jsp + ((size_t)t * 8 + c8) * 33 + k2 * 11;
                #pragma unroll
                for (int i = 0; i < 11; i++) row[i] += pp[i];
            }
            float acc = row[10];
            #pragma unroll
            for (int l = 0; l < kNB; l++) acc += bt[l] * row[l];
            Jr[t][k2] = acc;
        }
    } else if (t < 41 + kJ) {
        int idx = t - kJ;
        if (idx < 17) {
            int k = kP + idx;
            float val = 0.f;
            if (idx < kNB)          val = betas[b * kNB + idx];
            else if (k == kP + kNB) val = 1.0f;
            aswz[a_idx(mtile, minr, k)] = f2bf(val);
        }
    }
    __syncthreads();

    if (t == 0) {
        const int par[kJ] = {-1,0,0,0,1,2,3,4,5,6,7,8,9,9,9,12,13,14,16,17,18,19,20,21};
        #pragma unroll
        for (int m = 0; m < 3; m++) {
            #pragma unroll
            for (int n = 0; n < 3; n++) G[0][m * 4 + n] = Rsh[0][m * 3 + n];
            G[0][m * 4 + 3] = Jr[0][m];
        }
        for (int i = 1; i < kJ; i++) {
            int p = par[i];
            float rel[3];
            #pragma unroll
            for (int k = 0; k < 3; k++) rel[k] = Jr[i][k] - Jr[p][k];
            #pragma unroll
            for (int m = 0; m < 3; m++) {
                float g0 = G[p][m * 4 + 0], g1 = G[p][m * 4 + 1], g2 = G[p][m * 4 + 2];
                #pragma unroll
                for (int n = 0; n < 3; n++) {
                    G[i][m * 4 + n] = g0 * Rsh[i][0 * 3 + n]
                                    + g1 * Rsh[i][1 * 3 + n]
                                    + g2 * Rsh[i][2 * 3 + n];
                }
                G[i][m * 4 + 3] = g0 * rel[0] + g1 * rel[1] + g2 * rel[2]
                                + G[p][m * 4 + 3];
            }
        }
    }
    __syncthreads();

    if (t < kJ) {
        float* jo = out + O_JOINTS + (size_t)b * (kJ * 3) + (size_t)t * 3;
        #pragma unroll
        for (int m = 0; m < 3; m++) {
            float g0 = G[t][m * 4 + 0], g1 = G[t][m * 4 + 1], g2 = G[t][m * 4 + 2];
            float tr = G[t][m * 4 + 3]
                     - (g0 * Jr[t][0] + g1 * Jr[t][1] + g2 * Jr[t][2]);
            Ash[t][m * 4 + 0] = g0;
            Ash[t][m * 4 + 1] = g1;
            Ash[t][m * 4 + 2] = g2;
            Ash[t][m * 4 + 3] = tr;
            jo[m] = G[t][m * 4 + 3] - G[0][m * 4 + 3];
        }
        if (t == 0) {
            #pragma unroll
            for (int k = 0; k < 3; k++) wsRoot[b * 3 + k] = G[0][k * 4 + 3];
        }
    }
    __syncthreads();

    // bf16 hi/lo B-operand fragment for k_lbs MFMA
    {
        short8 h8, l8;
        #pragma unroll
        for (int e = 0; e < 8; e++) {
            int j = (t >> 4) * 8 + e;
            int m = t & 15;
            float val = (j < kJ && m < 12) ? Ash[j][m] : 0.f;
            unsigned short h = f2bf(val);
            h8[e] = (short)h;
            l8[e] = (short)f2bf(val - bf2f(h));
        }
        *(short8*)(abhi + (size_t)b * 512 + t * 8) = h8;
        *(short8*)(ablo + (size_t)b * 512 + t * 8) = l8;
    }
}

// ---------------------------------------------------------------------------
// k_gemm: v_posed[b][n] = A(1024x224) @ B(224x20670) -> out[O_VERTS] (fp32).
// ---------------------------------------------------------------------------
__global__ __launch_bounds__(256) void k_gemm(
    const unsigned short* __restrict__ A,
    const unsigned short* __restrict__ B,
    float* __restrict__ out)
{
    int tid = threadIdx.x;
    int lane = tid & 63;
    int wid = tid >> 6;
    int m0t = blockIdx.y * 8 + (wid >> 1) * 4;
    int n0t = blockIdx.x * 8 + (wid & 1) * 4;

    float4v acc[4][4];
    #pragma unroll
    for (int i = 0; i < 4; i++)
        #pragma unroll
        for (int j = 0; j < 4; j++)
            acc[i][j] = (float4v){0.f, 0.f, 0.f, 0.f};

    #pragma unroll
    for (int kt = 0; kt < 7; kt++) {
        short8 a[4], b[4];
        #pragma unroll
        for (int i = 0; i < 4; i++)
            a[i] = *(const short8*)(A + ((size_t)(m0t + i) * 7 + kt) * 512 + lane * 8);
        #pragma unroll
        for (int j = 0; j < 4; j++)
            b[j] = *(const short8*)(B + ((size_t)(n0t + j) * 7 + kt) * 512 + lane * 8);
        #pragma unroll
        for (int i = 0; i < 4; i++)
            #pragma unroll
            for (int j = 0; j < 4; j++)
                acc[i][j] = __builtin_amdgcn_mfma_f32_16x16x32_bf16(
                    a[i], b[j], acc[i][j], 0, 0, 0);
    }

    int rbase = (lane >> 4) * 4;
    int col = lane & 15;
    #pragma unroll
    for (int i = 0; i < 4; i++) {
        #pragma unroll
        for (int j = 0; j < 4; j++) {
            int n = (n0t + j) * 16 + col;
            if (n < kN) {
                #pragma unroll
                for (int reg = 0; reg < 4; reg++) {
                    int brow = (m0t + i) * 16 + rbase + reg;
                    out[O_VERTS + (size_t)brow * kN + n] = acc[i][j][reg];
                }
            }
        }
    }
}

// ---------------------------------------------------------------------------
// k_tr: jht[v*20 + j] = Jh[j*kV + v]  (pad-20 rows => every row 16B-aligned).
// Runs after k_gemm (bswz dead) -- jht overlays bswz.  ~1 MB RW, a few us.
// ---------------------------------------------------------------------------
__global__ __launch_bounds__(256) void k_tr(
    const float* __restrict__ Jh,
    float* __restrict__ jht)
{
    int v = blockIdx.x * 256 + threadIdx.x;
    if (v >= kV) return;
    #pragma unroll
    for (int j = 0; j < kH; j++)
        jht[(size_t)v * 20 + j] = Jh[(size_t)j * kV + v];
}

// ---------------------------------------------------------------------------
// k_lbs (MFMA): Tv(256v x 12) = W_tile @ A_flat on matrix cores, hi/lo bf16
// split (3 MFMAs; dropped Wlo@Alo <= 2^-18 rel).  W fragments in-register.
// (r9-verified: dropped out of top-5.)
// ---------------------------------------------------------------------------
__global__ __launch_bounds__(256) void k_lbs(
    const float* __restrict__ amb0,
    const float* __restrict__ amb1,
    const unsigned short* __restrict__ abhi,
    const unsigned short* __restrict__ ablo,
    const float* __restrict__ wsRoot,
    float* __restrict__ out)
{
    const float* W = amb0_is_weights(amb0) ? amb0 : amb1;
    __shared__ float ldsT[256 * 13];

    int t = threadIdx.x;
    int lane = t & 63, w = t >> 6;
    int vb = blockIdx.x;            // 0..26
    int b0 = blockIdx.y * kLbsTB;
    int chunk = lane >> 4;          // k-slice 0..3 (3 = pad)

    short8 wh[4], wl[4];
    #pragma unroll
    for (int i = 0; i < 4; i++) {
        int row = vb * 256 + (w * 4 + i) * 16 + (lane & 15);
        float vals[8];
        if (chunk < 3 && row < kV) {
            const float4v* p = (const float4v*)(W + (size_t)row * kJ + chunk * 8);
            float4v x0 = p[0], x1 = p[1];
            vals[0] = x0[0]; vals[1] = x0[1]; vals[2] = x0[2]; vals[3] = x0[3];
            vals[4] = x1[0]; vals[5] = x1[1]; vals[6] = x1[2]; vals[7] = x1[3];
        } else {
            #pragma unroll
            for (int e = 0; e < 8; e++) vals[e] = 0.f;
        }
        #pragma unroll
        for (int e = 0; e < 8; e++) {
            unsigned short h = f2bf(vals[e]);
            wh[i][e] = (short)h;
            wl[i][e] = (short)f2bf(vals[e] - bf2f(h));
        }
    }

    int v = vb * 256 + t;
    bool act = (v < kV);
    int crow = (lane >> 4) * 4;
    int ccol = lane & 15;

    #pragma unroll 1
    for (int tb = 0; tb < kLbsTB; tb++) {
        int b = b0 + tb;
        short8 ah = *(const short8*)(abhi + (size_t)b * 512 + lane * 8);
        short8 al = *(const short8*)(ablo + (size_t)b * 512 + lane * 8);

        #pragma unroll
        for (int i = 0; i < 4; i++) {
            float4v acc = (float4v){0.f, 0.f, 0.f, 0.f};
            acc = __builtin_amdgcn_mfma_f32_16x16x32_bf16(wl[i], ah, acc, 0, 0, 0);
            acc = __builtin_amdgcn_mfma_f32_16x16x32_bf16(wh[i], al, acc, 0, 0, 0);
            acc = __builtin_amdgcn_mfma_f32_16x16x32_bf16(wh[i], ah, acc, 0, 0, 0);
            if (ccol < 12) {
                int base = (w * 4 + i) * 16 * 13;
                #pragma unroll
                for (int reg = 0; reg < 4; reg++)
                    ldsT[base + (crow + reg) * 13 + ccol] = acc[reg];
            }
        }
        __syncthreads();

        {
            const float* T = &ldsT[t * 13];
            float r0 = wsRoot[(size_t)b * 3 + 0];
            float r1 = wsRoot[(size_t)b * 3 + 1];
            float r2 = wsRoot[(size_t)b * 3 + 2];
            if (act) {
                float* op = out + O_VERTS + ((size_t)b * kV + v) * 3;
                float x = op[0], y = op[1], z = op[2];
                float o0 = T[0] * x + T[1] * y + T[2]  * z + T[3]  - r0;
                float o1 = T[4] * x + T[5] * y + T[6]  * z + T[7]  - r1;
                float o2 = T[8] * x + T[9] * y + T[10] * z + T[11] - r2;
                op[0] = o0; op[1] = o1; op[2] = o2;
            }
        }
        __syncthreads();
    }
}

// ---------------------------------------------------------------------------
// k_jfv v4: jfv = JhT @ verts, root17 folded in.  BARRIER-FREE body.
// r11 counters (v3: 52.5us, VALUBusy 27%, occ 41%) -> latency-bound on 17
// scalar Jh row-streams + 3 verts loads per iter (20 loads x ~200cyc L2).
// v4: transposed padded jht (rows 80B, 16B-aligned): 4x float4 + 1 scalar
// per vertex (~8 loads, 5 vectorized).  512-thr blocks (2 batches x 4
// slices), grid 512: ~85 VGPR -> 2 blocks/CU = 16 waves.
// ---------------------------------------------------------------------------
__global__ __launch_bounds__(512) void k_jfv(
    const float* __restrict__ jht,
    const float* __restrict__ verts,
    float* __restrict__ out)
{
    __shared__ float part[8][kH * 3];

    int b0 = blockIdx.x * kJfvTB;
    int t = threadIdx.x;
    int wave = t >> 6, lane = t & 63;
    int bb = wave >> 2;             // batch 0..1
    int sl = wave & 3;              // verts slice 0..3

    const float* vbase = verts + (size_t)(b0 + bb) * kV * 3;

    float acc[kH][3];
    #pragma unroll
    for (int r = 0; r < kH; r++)
        #pragma unroll
        for (int k = 0; k < 3; k++) acc[r][k] = 0.f;

    int vend = min(kSL * (sl + 1), kV);
    for (int v = kSL * sl + lane; v < vend; v += 64) {
        const float4v* jp = (const float4v*)(jht + (size_t)v * 20);
        float4v j0 = jp[0], j1 = jp[1], j2 = jp[2], j3 = jp[3];
        float j16 = jht[(size_t)v * 20 + 16];
        const float* vp = vbase + (size_t)v * 3;
        float vx = vp[0], vy = vp[1], vz = vp[2];
        float jw[kH] = {j0[0], j0[1], j0[2], j0[3],
                        j1[0], j1[1], j1[2], j1[3],
                        j2[0], j2[1], j2[2], j2[3],
                        j3[0], j3[1], j3[2], j3[3], j16};
        #pragma unroll
        for (int r = 0; r < kH; r++) {
            acc[r][0] += jw[r] * vx;
            acc[r][1] += jw[r] * vy;
            acc[r][2] += jw[r] * vz;
        }
    }

    #pragma unroll
    for (int off = 32; off > 0; off >>= 1) {
        #pragma unroll
        for (int r = 0; r < kH; r++)
            #pragma unroll
            for (int k = 0; k < 3; k++)
                acc[r][k] += __shfl_down(acc[r][k], off, 64);
    }
    if (lane == 0) {
        #pragma unroll
        for (int r = 0; r < kH; r++)
            #pragma unroll
            for (int k = 0; k < 3; k++)
                part[wave][r * 3 + k] = acc[r][k];
    }
    __syncthreads();
    if (t < kJfvTB * (kH * 3)) {
        int b2 = t / (kH * 3), i = t - b2 * (kH * 3);
        float s  = part[b2 * 4 + 0][i] + part[b2 * 4 + 1][i]
                 + part[b2 * 4 + 2][i] + part[b2 * 4 + 3][i];
        int k = i % 3;
        float sk = part[b2 * 4 + 0][k] + part[b2 * 4 + 1][k]
                 + part[b2 * 4 + 2][k] + part[b2 * 4 + 3][k];
        // verts already root-subtracted; subtracting the per-axis j'=0 sums
        // reproduces jfv - root17 exactly (Jh rows sum to 1)
        out[O_JFV + (size_t)(b0 + b2) * 51 + i] = s - sk;
    }
}

extern "C" void kernel_launch(void* const* d_in, const int* in_sizes, int n_in,
                              void* d_out, int out_size, void* d_ws, size_t ws_size,
                              hipStream_t stream) {
    const float *pose = nullptr, *betas = nullptr, *gor = nullptr, *vt = nullptr,
                *sd = nullptr, *pd = nullptr, *Jh = nullptr;
    const float *amb0 = nullptr, *amb1 = nullptr;
    for (int i = 0; i < n_in; i++) {
        const float* p = (const float*)d_in[i];
        switch (in_sizes[i]) {
            case 70656:   pose  = p; break;
            case 10240:   betas = p; break;
            case 3072:    gor   = p; break;
            case 20670:   vt    = p; break;
            case 206700:  sd    = p; break;
            case 4278690: pd    = p; break;
            case 117130:  Jh    = p; break;
            case 165360:  if (!amb0) amb0 = p; else amb1 = p; break;
            default: break;
        }
    }

    float* ws = (float*)d_ws;
    float* jsp     = ws + WS_JSP;
    float* wsRoot  = ws + WS_ROOT;
    unsigned short* abhi = (unsigned short*)(ws + WS_ABHI);
    unsigned short* ablo = (unsigned short*)(ws + WS_ABLO);
    unsigned short* aswz = (unsigned short*)(ws + WS_ASWZ);
    unsigned short* bswz = (unsigned short*)(ws + WS_BSWZ);
    float* jht     = ws + WS_JHT;   // overlays bswz (dead after k_gemm)

    float* out = (float*)d_out;

    k_sfb  <<<dim3(kJsBlocks + kPbBlocks), dim3(256), 0, stream>>>(
        amb0, amb1, sd, vt, pd, jsp, bswz);
    k_pose <<<dim3(kB),                 dim3(64),  0, stream>>>(
        pose, betas, gor, jsp, wsRoot, aswz, abhi, ablo, out);
    k_gemm <<<dim3(kNT / 8, kB / 128),  dim3(256), 0, stream>>>(aswz, bswz, out);
    k_tr   <<<dim3((kV + 255) / 256),   dim3(256), 0, stream>>>(Jh, jht);
    k_lbs  <<<dim3(27, kB / kLbsTB),    dim3(256), 0, stream>>>(
        amb0, amb1, abhi, ablo, wsRoot, out);
    k_jfv  <<<dim3(kB / kJfvTB),        dim3(512), 0, stream>>>(
        jht, out + O_VERTS, out);
}